// Round 3
// baseline (233.136 us; speedup 1.0000x reference)
//
#include <hip/hip_runtime.h>
#include <hip/hip_cooperative_groups.h>

namespace cg = cooperative_groups;

// Problem constants: B=4, L=512, D=128, C=128
#define NB 4
#define SL 512
#define DD 128
#define CC 128

__device__ __forceinline__ float fexp2(float x) { return __builtin_amdgcn_exp2f(x); }
__device__ __forceinline__ float frcp(float x)  { return __builtin_amdgcn_rcpf(x); }

// ===========================================================================
// Fused cooperative kernel (ws-free). 512 blocks x 1024 threads = 2/CU.
// F (= exp(2*kx)^T, [B][C][L]) lives in the OUT buffer (both exactly 1 MB);
// E rows are computed locally per block. grid.sync #1 gates F-ready,
// grid.sync #2 gates all-F-consumed before out is overwritten.
// Budget theory: the 41 us fillBuffer seen every iteration is the harness
// re-poisoning d_ws; going ws-free tests whether that cost is conditional.
// ===========================================================================
__global__ __launch_bounds__(1024, 8) void fused_kernel(
    const float* __restrict__ inps, const float* __restrict__ wei_t,
    const float* __restrict__ wei_x, const float* __restrict__ bxh,
    const float* __restrict__ wei_a, float* __restrict__ outF)
{
    __shared__ float4 upk[CC];             // E quads {E[i0..i0+3, c]}   (2 KB)
    __shared__ float pool[4 * 32 * DD];    // 64 KB: F-transpose / c-merge / D partials
    __shared__ float scT[SL * 4];          // a[i][j] stored [j][4]      (8 KB)
    __shared__ float redw[4 * 4];

    const float K2 = 2.8853900817779268f;  // 2*log2(e)
    const int blk = blockIdx.x;            // 512 blocks
    const int b   = blk >> 7;
    const int i0  = (blk & 127) * 4;
    const int bi0 = b * SL + i0;
    const int tid = threadIdx.x;

    // ---- Phase P: projections for OUR 4 rows (one dot per thread) ----
    {
        const int mat = tid >> 9;          // 0 -> wei_t (E), 1 -> wei_x (F)
        const int r   = (tid >> 7) & 3;    // row within quad (wave-uniform)
        const int c   = tid & 127;
        const float* W  = mat ? wei_x : wei_t;
        const float* rp = inps + (size_t)(bi0 + r) * DD;   // uniform -> s_load
        float acc = 0.f;
        #pragma unroll 16
        for (int k = 0; k < DD; ++k)
            acc = fmaf(rp[k], W[k * CC + c], acc);
        if (mat == 0) {
            ((float*)&upk[c])[r] = fexp2(K2 * (acc + bxh[c]));
        } else {
            pool[c * 5 + r] = fexp2(K2 * acc);   // stride 5: bank-spread
        }
    }
    __syncthreads();                       // pool F-slice + upk ready
    if (tid < CC) {                        // transpose-store F quad to out-buffer
        float4 f = {pool[tid * 5 + 0], pool[tid * 5 + 1],
                    pool[tid * 5 + 2], pool[tid * 5 + 3]};
        *reinterpret_cast<float4*>(&outF[((size_t)b * CC + tid) * SL + i0]) = f;
    }
    cg::this_grid().sync();                // grid barrier 1: all F visible

    // ---- Phase B: partial s over this thread's 32-c quarter, 4 i x 2 j ----
    // (byte-identical math to the proven round-0 kernel; fits 64-VGPR cap)
    const int jt = tid & 255;              // j-pair index
    const int cq = tid >> 8;               // c-quarter (wave-uniform)
    const int j0 = jt * 2;
    const int c0 = cq * 32;
    const float* fb = outF + ((size_t)b * CC + c0) * SL + j0;
    const float4* up = upk + c0;
    const float* wa = wei_a + c0;          // uniform -> s_load
    float sx[4] = {0.f, 0.f, 0.f, 0.f};
    float sy[4] = {0.f, 0.f, 0.f, 0.f};
    #pragma unroll 4
    for (int cp = 0; cp < 16; ++cp) {
        float2 f0 = *reinterpret_cast<const float2*>(&fb[(size_t)(2 * cp) * SL]);
        float2 f1 = *reinterpret_cast<const float2*>(&fb[(size_t)(2 * cp + 1) * SL]);
        float4 u0 = up[2 * cp];            // broadcast ds_read_b128
        float4 u1 = up[2 * cp + 1];
        float wa0 = wa[2 * cp], wa1 = wa[2 * cp + 1];
        const float* u0p = reinterpret_cast<const float*>(&u0);
        const float* u1p = reinterpret_cast<const float*>(&u1);
        #pragma unroll
        for (int i = 0; i < 4; ++i) {
            float ax = fmaf(u0p[i], f0.x, 1.0f);
            float bx = fmaf(u1p[i], f1.x, 1.0f);
            float numx = fmaf(wa0, bx, wa1 * ax);
            sx[i] = fmaf(numx, frcp(ax * bx), sx[i]);
            float ay = fmaf(u0p[i], f0.y, 1.0f);
            float by = fmaf(u1p[i], f1.y, 1.0f);
            float numy = fmaf(wa0, by, wa1 * ay);
            sy[i] = fmaf(numy, frcp(ay * by), sy[i]);
        }
    }
    {   // park ALL quarters (stride 9: 2-way max per bank = free per m136)
        float* m = &pool[cq * 2304 + jt * 9];
        #pragma unroll
        for (int i = 0; i < 4; ++i) { m[i] = sx[i]; m[4 + i] = sy[i]; }
    }
    __syncthreads();                       // partials parked

    // ---- Phase C: merge + exp + row-sum + normalize, ALL 16 waves ----
    // (was 4 waves + 12 idle; thread t owns (j-pair jp, row i))
    {
        const int jp = tid & 255;
        const int i  = tid >> 8;           // 0..3 (wave-uniform)
        float sxx = 0.f, syy = 0.f;
        #pragma unroll
        for (int seg = 0; seg < 4; ++seg) {
            const float* m = &pool[seg * 2304 + jp * 9];
            sxx += m[i]; syy += m[4 + i];
        }
        const float KE = -2.8853900817779268f;  // -2*log2(e)
        float ex = fexp2(sxx * KE);
        float ey = fexp2(syy * KE);
        float t = ex + ey;
        #pragma unroll
        for (int off = 32; off > 0; off >>= 1)
            t += __shfl_xor(t, off, 64);
        if ((tid & 63) == 0) redw[i * 4 + ((tid >> 6) & 3)] = t;
        __syncthreads();                   // redw ready
        float S = redw[i * 4 + 0] + redw[i * 4 + 1]
                + redw[i * 4 + 2] + redw[i * 4 + 3];
        float rS = frcp(S + 1e-7f);
        scT[(jp * 2    ) * 4 + i] = ex * rS;
        scT[(jp * 2 + 1) * 4 + i] = ey * rS;
    }
    __syncthreads();                       // scT ready, pool free

    // ---- Phase D: a @ inps partials, ALL 32 waves (16 j per thread) ----
    {
        const int dq = (tid & 31) * 4;
        const int jq = tid >> 5;           // 0..31
        const float* ibase = inps + (size_t)b * SL * DD;
        float4 acc0 = {0,0,0,0}, acc1 = {0,0,0,0}, acc2 = {0,0,0,0}, acc3 = {0,0,0,0};
        const int jb = jq * 16;
        #pragma unroll 4
        for (int jj = 0; jj < 16; ++jj) {
            int jx = jb + jj;
            float4 v  = *reinterpret_cast<const float4*>(ibase + (size_t)jx * DD + dq);
            float4 a4 = *reinterpret_cast<const float4*>(&scT[jx * 4]);  // broadcast
            acc0.x = fmaf(a4.x, v.x, acc0.x); acc0.y = fmaf(a4.x, v.y, acc0.y);
            acc0.z = fmaf(a4.x, v.z, acc0.z); acc0.w = fmaf(a4.x, v.w, acc0.w);
            acc1.x = fmaf(a4.y, v.x, acc1.x); acc1.y = fmaf(a4.y, v.y, acc1.y);
            acc1.z = fmaf(a4.y, v.z, acc1.z); acc1.w = fmaf(a4.y, v.w, acc1.w);
            acc2.x = fmaf(a4.z, v.x, acc2.x); acc2.y = fmaf(a4.z, v.y, acc2.y);
            acc2.z = fmaf(a4.z, v.z, acc2.z); acc2.w = fmaf(a4.z, v.w, acc2.w);
            acc3.x = fmaf(a4.w, v.x, acc3.x); acc3.y = fmaf(a4.w, v.y, acc3.y);
            acc3.z = fmaf(a4.w, v.z, acc3.z); acc3.w = fmaf(a4.w, v.w, acc3.w);
        }
        *reinterpret_cast<float4*>(&pool[(0 * 32 + jq) * DD + dq]) = acc0;
        *reinterpret_cast<float4*>(&pool[(1 * 32 + jq) * DD + dq]) = acc1;
        *reinterpret_cast<float4*>(&pool[(2 * 32 + jq) * DD + dq]) = acc2;
        *reinterpret_cast<float4*>(&pool[(3 * 32 + jq) * DD + dq]) = acc3;
    }
    cg::this_grid().sync();                // grid barrier 2: all F-reads done
                                           // (also block-local barrier for pool)

    // ---- Phase E: reduce partials, overwrite out ----
    if (tid < 512) {
        int i = tid >> 7, d = tid & 127;
        float sum = 0.f;
        #pragma unroll
        for (int q = 0; q < 32; ++q) sum += pool[(i * 32 + q) * DD + d];
        outF[(size_t)(bi0 + i) * DD + d] = sum;
    }
}

// ===========================================================================
// Fallback path (proven round-0/2 kernels, uses d_ws) in case cooperative
// launch is rejected under graph capture.
// ===========================================================================
__global__ __launch_bounds__(512) void proj_kernel(
    const float* __restrict__ inps, const float* __restrict__ wei_t,
    const float* __restrict__ wei_x, const float* __restrict__ bxh,
    float* __restrict__ E, float* __restrict__ F)
{
    __shared__ float part[2 * 128 * 5];
    const float K2 = 2.8853900817779268f;
    const int row0 = blockIdx.x * 4;
    const int b    = row0 >> 9;
    const int i0   = row0 & 511;
    const int tid  = threadIdx.x;
    const int c    = tid & 127;
    const int sel  = (tid >> 7) & 1;
    const int kh   = tid >> 8;

    const float* W = (sel ? wei_x : wei_t) + kh * 64 * CC;
    const float* r = inps + (size_t)row0 * DD + kh * 64;

    float a0 = 0.f, a1 = 0.f, a2 = 0.f, a3 = 0.f;
    #pragma unroll 16
    for (int k = 0; k < 64; ++k) {
        float w = W[k * CC + c];
        a0 = fmaf(r[k         ], w, a0);
        a1 = fmaf(r[DD     + k], w, a1);
        a2 = fmaf(r[2 * DD + k], w, a2);
        a3 = fmaf(r[3 * DD + k], w, a3);
    }
    if (kh == 1) {
        float* m = &part[(sel * 128 + c) * 5];
        m[0] = a0; m[1] = a1; m[2] = a2; m[3] = a3;
    }
    __syncthreads();
    if (kh == 0) {
        const float* m = &part[(sel * 128 + c) * 5];
        a0 += m[0]; a1 += m[1]; a2 += m[2]; a3 += m[3];
        if (sel == 0) {
            float bb = bxh[c];
            E[(size_t)(row0 + 0) * CC + c] = fexp2(K2 * (a0 + bb));
            E[(size_t)(row0 + 1) * CC + c] = fexp2(K2 * (a1 + bb));
            E[(size_t)(row0 + 2) * CC + c] = fexp2(K2 * (a2 + bb));
            E[(size_t)(row0 + 3) * CC + c] = fexp2(K2 * (a3 + bb));
        } else {
            float4 v = {fexp2(K2 * a0), fexp2(K2 * a1), fexp2(K2 * a2), fexp2(K2 * a3)};
            *reinterpret_cast<float4*>(&F[((size_t)b * CC + c) * SL + i0]) = v;
        }
    }
}

__global__ __launch_bounds__(1024, 8) void attn_kernel(
    const float* __restrict__ inps, const float* __restrict__ wei_a,
    const float* __restrict__ E, const float* __restrict__ F,
    float* __restrict__ out)
{
    __shared__ float4 upk[CC];
    __shared__ float pool[4 * 16 * DD];
    __shared__ float scT[SL * 4];
    __shared__ float redw[4 * 4];

    const int blk = blockIdx.x;
    const int b   = blk >> 7;
    const int i0  = (blk & 127) * 4;
    const int bi0 = b * SL + i0;
    const int tid = threadIdx.x;
    const int jt  = tid & 255;
    const int cq  = tid >> 8;
    const int j0  = jt * 2;

    if (tid < CC) {
        float4 u;
        u.x = E[(size_t)(bi0 + 0) * CC + tid];
        u.y = E[(size_t)(bi0 + 1) * CC + tid];
        u.z = E[(size_t)(bi0 + 2) * CC + tid];
        u.w = E[(size_t)(bi0 + 3) * CC + tid];
        upk[tid] = u;
    }
    __syncthreads();

    const int c0 = cq * 32;
    const float* fb = F + ((size_t)b * CC + c0) * SL + j0;
    const float4* up = upk + c0;
    const float* wa = wei_a + c0;
    float sx[4] = {0.f, 0.f, 0.f, 0.f};
    float sy[4] = {0.f, 0.f, 0.f, 0.f};
    #pragma unroll 4
    for (int cp = 0; cp < 16; ++cp) {
        float2 f0 = *reinterpret_cast<const float2*>(&fb[(size_t)(2 * cp) * SL]);
        float2 f1 = *reinterpret_cast<const float2*>(&fb[(size_t)(2 * cp + 1) * SL]);
        float4 u0 = up[2 * cp];
        float4 u1 = up[2 * cp + 1];
        float wa0 = wa[2 * cp], wa1 = wa[2 * cp + 1];
        const float* u0p = reinterpret_cast<const float*>(&u0);
        const float* u1p = reinterpret_cast<const float*>(&u1);
        #pragma unroll
        for (int i = 0; i < 4; ++i) {
            float ax = fmaf(u0p[i], f0.x, 1.0f);
            float bx = fmaf(u1p[i], f1.x, 1.0f);
            float numx = fmaf(wa0, bx, wa1 * ax);
            sx[i] = fmaf(numx, frcp(ax * bx), sx[i]);
            float ay = fmaf(u0p[i], f0.y, 1.0f);
            float by = fmaf(u1p[i], f1.y, 1.0f);
            float numy = fmaf(wa0, by, wa1 * ay);
            sy[i] = fmaf(numy, frcp(ay * by), sy[i]);
        }
    }
    if (cq > 0) {
        float* m = &pool[(cq - 1) * 2304 + jt * 9];
        #pragma unroll
        for (int i = 0; i < 4; ++i) { m[i] = sx[i]; m[4 + i] = sy[i]; }
    }
    __syncthreads();

    if (cq == 0) {
        #pragma unroll
        for (int seg = 0; seg < 3; ++seg) {
            const float* m = &pool[seg * 2304 + jt * 9];
            #pragma unroll
            for (int i = 0; i < 4; ++i) { sx[i] += m[i]; sy[i] += m[4 + i]; }
        }
        const float KE = -2.8853900817779268f;
        float ex[4], ey[4];
        const int lane = tid & 63, wv = tid >> 6;
        #pragma unroll
        for (int i = 0; i < 4; ++i) {
            ex[i] = fexp2(sx[i] * KE);
            ey[i] = fexp2(sy[i] * KE);
            float t = ex[i] + ey[i];
            #pragma unroll
            for (int off = 32; off > 0; off >>= 1)
                t += __shfl_xor(t, off, 64);
            if (lane == 0) redw[i * 4 + wv] = t;
        }
        __syncthreads();
        float4 av0, av1;
        {
            float S0 = redw[0] + redw[1] + redw[2] + redw[3];
            float S1 = redw[4] + redw[5] + redw[6] + redw[7];
            float S2 = redw[8] + redw[9] + redw[10] + redw[11];
            float S3 = redw[12] + redw[13] + redw[14] + redw[15];
            float r0 = frcp(S0 + 1e-7f), r1 = frcp(S1 + 1e-7f);
            float r2 = frcp(S2 + 1e-7f), r3 = frcp(S3 + 1e-7f);
            av0 = make_float4(ex[0] * r0, ex[1] * r1, ex[2] * r2, ex[3] * r3);
            av1 = make_float4(ey[0] * r0, ey[1] * r1, ey[2] * r2, ey[3] * r3);
        }
        *reinterpret_cast<float4*>(&scT[j0 * 4])     = av0;
        *reinterpret_cast<float4*>(&scT[j0 * 4 + 4]) = av1;
    } else {
        __syncthreads();
    }
    __syncthreads();

    if (tid < 512) {
        const int dq = (tid & 31) * 4;
        const int jq = tid >> 5;
        const float* ibase = inps + (size_t)b * SL * DD;
        float4 acc0 = {0,0,0,0}, acc1 = {0,0,0,0}, acc2 = {0,0,0,0}, acc3 = {0,0,0,0};
        const int jb = jq * 32;
        #pragma unroll 4
        for (int jj = 0; jj < 32; ++jj) {
            int jx = jb + jj;
            float4 v  = *reinterpret_cast<const float4*>(ibase + (size_t)jx * DD + dq);
            float4 a4 = *reinterpret_cast<const float4*>(&scT[jx * 4]);
            acc0.x = fmaf(a4.x, v.x, acc0.x); acc0.y = fmaf(a4.x, v.y, acc0.y);
            acc0.z = fmaf(a4.x, v.z, acc0.z); acc0.w = fmaf(a4.x, v.w, acc0.w);
            acc1.x = fmaf(a4.y, v.x, acc1.x); acc1.y = fmaf(a4.y, v.y, acc1.y);
            acc1.z = fmaf(a4.y, v.z, acc1.z); acc1.w = fmaf(a4.y, v.w, acc1.w);
            acc2.x = fmaf(a4.z, v.x, acc2.x); acc2.y = fmaf(a4.z, v.y, acc2.y);
            acc2.z = fmaf(a4.z, v.z, acc2.z); acc2.w = fmaf(a4.z, v.w, acc2.w);
            acc3.x = fmaf(a4.w, v.x, acc3.x); acc3.y = fmaf(a4.w, v.y, acc3.y);
            acc3.z = fmaf(a4.w, v.z, acc3.z); acc3.w = fmaf(a4.w, v.w, acc3.w);
        }
        *reinterpret_cast<float4*>(&pool[(0 * 16 + jq) * DD + dq]) = acc0;
        *reinterpret_cast<float4*>(&pool[(1 * 16 + jq) * DD + dq]) = acc1;
        *reinterpret_cast<float4*>(&pool[(2 * 16 + jq) * DD + dq]) = acc2;
        *reinterpret_cast<float4*>(&pool[(3 * 16 + jq) * DD + dq]) = acc3;
    }
    __syncthreads();
    if (tid < 512) {
        int i = tid >> 7, d = tid & 127;
        float sum = 0.f;
        #pragma unroll
        for (int q = 0; q < 16; ++q) sum += pool[(i * 16 + q) * DD + d];
        out[(size_t)(bi0 + i) * DD + d] = sum;
    }
}

extern "C" void kernel_launch(void* const* d_in, const int* in_sizes, int n_in,
                              void* d_out, int out_size, void* d_ws, size_t ws_size,
                              hipStream_t stream) {
    const float* inps  = (const float*)d_in[0];  // [B, L, D]
    const float* wei_t = (const float*)d_in[1];  // [D, C]
    const float* wei_x = (const float*)d_in[2];  // [D, C]
    const float* bxh   = (const float*)d_in[3];  // [C]
    const float* wei_a = (const float*)d_in[4];  // [C]
    // d_in[5] = bxa (scalar): uniform shift before softmax -> dropped.
    float* out = (float*)d_out;                  // [B, L, D] fp32 (doubles as F)

    void* args[] = {(void*)&inps, (void*)&wei_t, (void*)&wei_x,
                    (void*)&bxh, (void*)&wei_a, (void*)&out};
    hipError_t err = hipLaunchCooperativeKernel(
        (const void*)fused_kernel, dim3(NB * SL / 4), dim3(1024), args, 0, stream);
    if (err != hipSuccess) {
        // Fallback: proven 2-kernel path through the workspace.
        float* E = (float*)d_ws;                 // [B*L, C]   1 MB
        float* F = E + (size_t)NB * SL * CC;     // [B, C, L]  1 MB
        proj_kernel<<<NB * SL / 4, 512, 0, stream>>>(inps, wei_t, wei_x, bxh, E, F);
        attn_kernel<<<NB * SL / 4, 1024, 0, stream>>>(inps, wei_a, E, F, out);
    }
}

// Round 4
// 96.799 us; speedup vs baseline: 2.4085x; 2.4085x over previous
//
#include <hip/hip_runtime.h>

// Problem constants: B=4, L=512, D=128, C=128
#define NB 4
#define SL 512
#define DD 128
#define CC 128

__device__ __forceinline__ float fexp2(float x) { return __builtin_amdgcn_exp2f(x); }
__device__ __forceinline__ float frcp(float x)  { return __builtin_amdgcn_rcpf(x); }

// Kernel 1: projections, EXPONENTIATED (trans factorization):
//   E  [B*L, C]  = exp2( K2 * (inps @ wei_t + bxh) )
//   F  [B, C, L] = exp2( K2 * (inps @ wei_x) )^T
// v3 (proven round 2): 4 rows/block, k-split across 512 threads, stride-5
// LDS merge. 512 blocks = 2/CU, 4 waves/SIMD.
__global__ __launch_bounds__(512) void proj_kernel(
    const float* __restrict__ inps, const float* __restrict__ wei_t,
    const float* __restrict__ wei_x, const float* __restrict__ bxh,
    float* __restrict__ E, float* __restrict__ F)
{
    __shared__ float part[2 * 128 * 5];    // [sel][c][4 partials], stride 5 (5 KB)
    const float K2 = 2.8853900817779268f;  // 2*log2(e)
    const int row0 = blockIdx.x * 4;       // global row = b*SL + i
    const int b    = row0 >> 9;
    const int i0   = row0 & 511;
    const int tid  = threadIdx.x;
    const int c    = tid & 127;
    const int sel  = (tid >> 7) & 1;       // wave-uniform: wei_t (E) vs wei_x (F)
    const int kh   = tid >> 8;             // wave-uniform: k-half

    const float* W = (sel ? wei_x : wei_t) + kh * 64 * CC;
    const float* r = inps + (size_t)row0 * DD + kh * 64;  // uniform -> s_load

    float a0 = 0.f, a1 = 0.f, a2 = 0.f, a3 = 0.f;
    #pragma unroll 16
    for (int k = 0; k < 64; ++k) {
        float w = W[k * CC + c];           // coalesced across c
        a0 = fmaf(r[k         ], w, a0);
        a1 = fmaf(r[DD     + k], w, a1);
        a2 = fmaf(r[2 * DD + k], w, a2);
        a3 = fmaf(r[3 * DD + k], w, a3);
    }

    if (kh == 1) {                         // upper k-half: park partials
        float* m = &part[(sel * 128 + c) * 5];
        m[0] = a0; m[1] = a1; m[2] = a2; m[3] = a3;
    }
    __syncthreads();
    if (kh == 0) {                         // lower k-half: merge + finalize
        const float* m = &part[(sel * 128 + c) * 5];
        a0 += m[0]; a1 += m[1]; a2 += m[2]; a3 += m[3];
        if (sel == 0) {
            float bb = bxh[c];
            E[(size_t)(row0 + 0) * CC + c] = fexp2(K2 * (a0 + bb));
            E[(size_t)(row0 + 1) * CC + c] = fexp2(K2 * (a1 + bb));
            E[(size_t)(row0 + 2) * CC + c] = fexp2(K2 * (a2 + bb));
            E[(size_t)(row0 + 3) * CC + c] = fexp2(K2 * (a3 + bb));
        } else {
            float4 v = {fexp2(K2 * a0), fexp2(K2 * a1), fexp2(K2 * a2), fexp2(K2 * a3)};
            *reinterpret_cast<float4*>(&F[((size_t)b * CC + c) * SL + i0]) = v;
        }
    }
}

// Kernel 2: one block per (b, 4 rows of i). 512 blocks x 1024 threads.
// v4 changes vs proven round-0/2 version:
//  - __launch_bounds__(1024, 4): VGPR cap 128 (was 64). Theory: phase B's
//    32 F-loads/thread were pipeline-starved at 64 VGPRs -> exposed L2
//    latency. 128 regs lets the compiler hoist/prefetch deeply. Occupancy
//    may drop to 1 block/CU (16 waves) if VGPR>64 -- acceptable trade.
//  - Phase C on all 16 waves (was 4 + 12 idle)  [verified correct in r3]
//  - Phase D on all 32 j-groups / full block (was half) [verified in r3]
//  - pool grows to 64 KB (4*32*DD) for 32 D-partial rows; LDS total
//    74.5 KB still allows 2 blocks/CU if VGPR<=64.
__global__ __launch_bounds__(1024, 4) void attn_kernel(
    const float* __restrict__ inps, const float* __restrict__ wei_a,
    const float* __restrict__ E, const float* __restrict__ F,
    float* __restrict__ out)
{
    __shared__ float4 upk[CC];             // E quads {E[i0..i0+3, c]}   (2 KB)
    __shared__ float pool[4 * 32 * DD];    // 64 KB: c-merge, then D partials
    __shared__ float scT[SL * 4];          // a[i][j] stored [j][4]      (8 KB)
    __shared__ float redw[4 * 4];          // 4 rows x 4 waves-per-row

    const int blk = blockIdx.x;            // 512 blocks
    const int b   = blk >> 7;
    const int i0  = (blk & 127) * 4;
    const int bi0 = b * SL + i0;
    const int tid = threadIdx.x;
    const int jt  = tid & 255;             // j-pair index
    const int cq  = tid >> 8;              // c-quarter (wave-uniform)
    const int j0  = jt * 2;

    // Phase A: stage the four block-uniform E rows as quads (128 threads)
    if (tid < CC) {
        float4 u;
        u.x = E[(size_t)(bi0 + 0) * CC + tid];
        u.y = E[(size_t)(bi0 + 1) * CC + tid];
        u.z = E[(size_t)(bi0 + 2) * CC + tid];
        u.w = E[(size_t)(bi0 + 3) * CC + tid];
        upk[tid] = u;
    }
    __syncthreads();                       // barrier 1

    // Phase B: partial s over this thread's 32-c quarter, 4 i's x 2 j's.
    // (math byte-identical to the round-0-proven kernel)
    const int c0 = cq * 32;
    const float* fb = F + ((size_t)b * CC + c0) * SL + j0;
    const float4* up = upk + c0;
    const float* wa = wei_a + c0;          // uniform -> s_load (K$ hot)
    float sx[4] = {0.f, 0.f, 0.f, 0.f};
    float sy[4] = {0.f, 0.f, 0.f, 0.f};
    #pragma unroll 4
    for (int cp = 0; cp < 16; ++cp) {
        float2 f0 = *reinterpret_cast<const float2*>(&fb[(size_t)(2 * cp) * SL]);
        float2 f1 = *reinterpret_cast<const float2*>(&fb[(size_t)(2 * cp + 1) * SL]);
        float4 u0 = up[2 * cp];            // broadcast ds_read_b128
        float4 u1 = up[2 * cp + 1];
        float wa0 = wa[2 * cp], wa1 = wa[2 * cp + 1];
        const float* u0p = reinterpret_cast<const float*>(&u0);
        const float* u1p = reinterpret_cast<const float*>(&u1);
        #pragma unroll
        for (int i = 0; i < 4; ++i) {
            float ax = fmaf(u0p[i], f0.x, 1.0f);
            float bx = fmaf(u1p[i], f1.x, 1.0f);
            float numx = fmaf(wa0, bx, wa1 * ax);
            sx[i] = fmaf(numx, frcp(ax * bx), sx[i]);
            float ay = fmaf(u0p[i], f0.y, 1.0f);
            float by = fmaf(u1p[i], f1.y, 1.0f);
            float numy = fmaf(wa0, by, wa1 * ay);
            sy[i] = fmaf(numy, frcp(ay * by), sy[i]);
        }
    }
    {   // park ALL quarters (stride 9: 2-way max per bank = free per m136)
        float* m = &pool[cq * 2304 + jt * 9];
        #pragma unroll
        for (int i = 0; i < 4; ++i) { m[i] = sx[i]; m[4 + i] = sy[i]; }
    }
    __syncthreads();                       // barrier 2: partials parked

    // Phase C: merge + exp + row-sum + normalize, ALL 16 waves.
    // Thread t owns (j-pair jp = t&255, row i = t>>8).  [r3-verified]
    {
        const int jp = tid & 255;
        const int i  = tid >> 8;           // 0..3 (wave-uniform)
        float sxx = 0.f, syy = 0.f;
        #pragma unroll
        for (int seg = 0; seg < 4; ++seg) {
            const float* m = &pool[seg * 2304 + jp * 9];
            sxx += m[i]; syy += m[4 + i];
        }
        const float KE = -2.8853900817779268f;  // -2*log2(e)
        float ex = fexp2(sxx * KE);
        float ey = fexp2(syy * KE);
        float t = ex + ey;
        #pragma unroll
        for (int off = 32; off > 0; off >>= 1)
            t += __shfl_xor(t, off, 64);
        if ((tid & 63) == 0) redw[i * 4 + ((tid >> 6) & 3)] = t;
        __syncthreads();                   // barrier 3: redw ready
        float S = redw[i * 4 + 0] + redw[i * 4 + 1]
                + redw[i * 4 + 2] + redw[i * 4 + 3];
        float rS = frcp(S + 1e-7f);
        scT[(jp * 2    ) * 4 + i] = ex * rS;
        scT[(jp * 2 + 1) * 4 + i] = ey * rS;
    }
    __syncthreads();                       // barrier 4: scT ready, pool free

    // Phase D: a @ inps partials, ALL 32 j-groups (16 j per thread). [r3-verified]
    {
        const int dq = (tid & 31) * 4;
        const int jq = tid >> 5;           // 0..31
        const float* ibase = inps + (size_t)b * SL * DD;
        float4 acc0 = {0,0,0,0}, acc1 = {0,0,0,0}, acc2 = {0,0,0,0}, acc3 = {0,0,0,0};
        const int jb = jq * 16;
        #pragma unroll 4
        for (int jj = 0; jj < 16; ++jj) {
            int jx = jb + jj;
            float4 v  = *reinterpret_cast<const float4*>(ibase + (size_t)jx * DD + dq);
            float4 a4 = *reinterpret_cast<const float4*>(&scT[jx * 4]);  // broadcast
            acc0.x = fmaf(a4.x, v.x, acc0.x); acc0.y = fmaf(a4.x, v.y, acc0.y);
            acc0.z = fmaf(a4.x, v.z, acc0.z); acc0.w = fmaf(a4.x, v.w, acc0.w);
            acc1.x = fmaf(a4.y, v.x, acc1.x); acc1.y = fmaf(a4.y, v.y, acc1.y);
            acc1.z = fmaf(a4.y, v.z, acc1.z); acc1.w = fmaf(a4.y, v.w, acc1.w);
            acc2.x = fmaf(a4.z, v.x, acc2.x); acc2.y = fmaf(a4.z, v.y, acc2.y);
            acc2.z = fmaf(a4.z, v.z, acc2.z); acc2.w = fmaf(a4.z, v.w, acc2.w);
            acc3.x = fmaf(a4.w, v.x, acc3.x); acc3.y = fmaf(a4.w, v.y, acc3.y);
            acc3.z = fmaf(a4.w, v.z, acc3.z); acc3.w = fmaf(a4.w, v.w, acc3.w);
        }
        *reinterpret_cast<float4*>(&pool[(0 * 32 + jq) * DD + dq]) = acc0;
        *reinterpret_cast<float4*>(&pool[(1 * 32 + jq) * DD + dq]) = acc1;
        *reinterpret_cast<float4*>(&pool[(2 * 32 + jq) * DD + dq]) = acc2;
        *reinterpret_cast<float4*>(&pool[(3 * 32 + jq) * DD + dq]) = acc3;
    }
    __syncthreads();                       // barrier 5

    // Phase E: reduce 32 partials per (i, d), write out.
    if (tid < 512) {
        int i = tid >> 7, d = tid & 127;   // 4 rows x 128 d
        float sum = 0.f;
        #pragma unroll
        for (int q = 0; q < 32; ++q) sum += pool[(i * 32 + q) * DD + d];
        out[(size_t)(bi0 + i) * DD + d] = sum;
    }
}

extern "C" void kernel_launch(void* const* d_in, const int* in_sizes, int n_in,
                              void* d_out, int out_size, void* d_ws, size_t ws_size,
                              hipStream_t stream) {
    const float* inps  = (const float*)d_in[0];  // [B, L, D]
    const float* wei_t = (const float*)d_in[1];  // [D, C]
    const float* wei_x = (const float*)d_in[2];  // [D, C]
    const float* bxh   = (const float*)d_in[3];  // [C]
    const float* wei_a = (const float*)d_in[4];  // [C]
    // d_in[5] = bxa (scalar): uniform shift before softmax -> dropped.
    float* out = (float*)d_out;                  // [B, L, D] fp32

    float* E = (float*)d_ws;                     // [B*L, C]   1 MB
    float* F = E + (size_t)NB * SL * CC;         // [B, C, L]  1 MB

    proj_kernel<<<NB * SL / 4, 512, 0, stream>>>(inps, wei_t, wei_x, bxh, E, F);
    attn_kernel<<<NB * SL / 4, 1024, 0, stream>>>(inps, wei_a, E, F, out);
}

// Round 5
// 90.725 us; speedup vs baseline: 2.5697x; 1.0670x over previous
//
#include <hip/hip_runtime.h>

// Problem constants: B=4, L=512, D=128, C=128
#define NB 4
#define SL 512
#define DD 128
#define CC 128

__device__ __forceinline__ float fexp2(float x) { return __builtin_amdgcn_exp2f(x); }
__device__ __forceinline__ float frcp(float x)  { return __builtin_amdgcn_rcpf(x); }

// Kernel 1: projections, EXPONENTIATED (trans factorization):
//   E  [B*L, C]  = exp2( K2 * (inps @ wei_t + bxh) )
//   F  [B, C, L] = exp2( K2 * (inps @ wei_x) )^T
// v1 (round-0 proven, best measured): 2 rows/block, 256 threads,
// 1024 blocks = 4 blocks/CU = 4 waves/SIMD. (v3's k-split measured
// +3.2 us slower across R0/R2 -> reverted.)
__global__ __launch_bounds__(256) void proj_kernel(
    const float* __restrict__ inps, const float* __restrict__ wei_t,
    const float* __restrict__ wei_x, const float* __restrict__ bxh,
    float* __restrict__ E, float* __restrict__ F)
{
    const float K2 = 2.8853900817779268f;  // 2*log2(e)
    const int row0 = blockIdx.x * 2;       // global row = b*SL + i
    const int b    = row0 >> 9;
    const int i0   = row0 & 511;
    const int c    = threadIdx.x & 127;
    const int sel  = threadIdx.x >> 7;     // wave-uniform: waves 0-1 wei_t, 2-3 wei_x

    const float* W  = sel ? wei_x : wei_t;
    const float* r0 = inps + (size_t)row0 * DD;   // uniform -> s_load
    const float* r1 = r0 + DD;

    float a0 = 0.f, a1 = 0.f;
    #pragma unroll 8
    for (int k = 0; k < DD; ++k) {
        float w = W[k * CC + c];           // coalesced across c
        a0 = fmaf(r0[k], w, a0);
        a1 = fmaf(r1[k], w, a1);
    }

    if (sel == 0) {
        float bb = bxh[c];
        E[(size_t)(row0 + 0) * CC + c] = fexp2(K2 * (a0 + bb));
        E[(size_t)(row0 + 1) * CC + c] = fexp2(K2 * (a1 + bb));
    } else {
        float2 v = {fexp2(K2 * a0), fexp2(K2 * a1)};
        *reinterpret_cast<float2*>(&F[((size_t)b * CC + c) * SL + i0]) = v;
    }
}

// Kernel 2 v5: one block per (b, 4 rows of i). 512 blocks x 512 threads.
// THE change vs round 0: 512-thread blocks with __launch_bounds__(512,4)
// -> 128-VGPR cap at the SAME 16 waves/CU (2 blocks/CU, LDS 42 KB).
// Round-0's (1024,8) left phase B at ~32 VGPRs (r1/r3 dispatch tables):
// zero slack over the live set -> loads issue nearly one-at-a-time, each
// exposing L2 latency. 1024-thread blocks can't escape (occupancy
// quantizes to 1 or 2 blocks/CU: 128 VGPR costs half the waves, r4 wash).
// At 512 thr: phase B covers a c-HALF per thread (64 c, 32 iters, 2-way
// LDS merge instead of 4-way); phases C/D/E keep round-0 shapes, now
// spanning the whole block (no idle waves at D/E).
__global__ __launch_bounds__(512, 4) void attn_kernel(
    const float* __restrict__ inps, const float* __restrict__ wei_a,
    const float* __restrict__ E, const float* __restrict__ F,
    float* __restrict__ out)
{
    __shared__ float4 upk[CC];             // E quads {E[i0..i0+3, c]}  (2 KB)
    __shared__ float pool[4 * 16 * DD];    // 32 KB: c-merge (B/C), then phase-D partials
    __shared__ float scT[SL * 4];          // a[i][j] stored [j][4]      (8 KB)
    __shared__ float redw[4 * 4];          // 4 rows x 4 waves

    const int blk = blockIdx.x;            // 512 blocks
    const int b   = blk >> 7;
    const int i0  = (blk & 127) * 4;
    const int bi0 = b * SL + i0;
    const int tid = threadIdx.x;
    const int jt  = tid & 255;             // j-pair index
    const int ch  = tid >> 8;              // c-half (wave-uniform)
    const int j0  = jt * 2;

    // Phase A: stage the four block-uniform E rows as quads (128 threads)
    if (tid < CC) {
        float4 u;
        u.x = E[(size_t)(bi0 + 0) * CC + tid];
        u.y = E[(size_t)(bi0 + 1) * CC + tid];
        u.z = E[(size_t)(bi0 + 2) * CC + tid];
        u.w = E[(size_t)(bi0 + 3) * CC + tid];
        upk[tid] = u;
    }
    __syncthreads();                       // barrier 1

    // Phase B: partial s over this thread's 64-c half, 4 i's x 2 j's.
    // (math per c-pair identical to the round-0-proven kernel)
    const int c0 = ch * 64;
    const float* fb = F + ((size_t)b * CC + c0) * SL + j0;
    const float4* up = upk + c0;
    const float* wa = wei_a + c0;          // uniform -> s_load (K$ hot)
    float sx[4] = {0.f, 0.f, 0.f, 0.f};
    float sy[4] = {0.f, 0.f, 0.f, 0.f};
    #pragma unroll 4
    for (int cp = 0; cp < 32; ++cp) {
        float2 f0 = *reinterpret_cast<const float2*>(&fb[(size_t)(2 * cp) * SL]);
        float2 f1 = *reinterpret_cast<const float2*>(&fb[(size_t)(2 * cp + 1) * SL]);
        float4 u0 = up[2 * cp];            // broadcast ds_read_b128
        float4 u1 = up[2 * cp + 1];
        float wa0 = wa[2 * cp], wa1 = wa[2 * cp + 1];
        const float* u0p = reinterpret_cast<const float*>(&u0);
        const float* u1p = reinterpret_cast<const float*>(&u1);
        #pragma unroll
        for (int i = 0; i < 4; ++i) {
            float ax = fmaf(u0p[i], f0.x, 1.0f);
            float bx = fmaf(u1p[i], f1.x, 1.0f);
            float numx = fmaf(wa0, bx, wa1 * ax);
            sx[i] = fmaf(numx, frcp(ax * bx), sx[i]);
            float ay = fmaf(u0p[i], f0.y, 1.0f);
            float by = fmaf(u1p[i], f1.y, 1.0f);
            float numy = fmaf(wa0, by, wa1 * ay);
            sy[i] = fmaf(numy, frcp(ay * by), sy[i]);
        }
    }

    // Park upper-half partials (stride 9: gcd(9,32)=1 -> 2-way max = free).
    if (ch == 1) {
        float* m = &pool[jt * 9];
        #pragma unroll
        for (int i = 0; i < 4; ++i) { m[i] = sx[i]; m[4 + i] = sy[i]; }
    }
    __syncthreads();                       // barrier 2: partials parked

    // Phase C (lower-half threads, 4 waves): merge + exp + row-sum + norm.
    if (ch == 0) {
        {
            const float* m = &pool[jt * 9];
            #pragma unroll
            for (int i = 0; i < 4; ++i) { sx[i] += m[i]; sy[i] += m[4 + i]; }
        }
        const float KE = -2.8853900817779268f;  // -2*log2(e)
        float ex[4], ey[4];
        const int lane = tid & 63, wv = tid >> 6;   // wv in 0..3
        #pragma unroll
        for (int i = 0; i < 4; ++i) {
            ex[i] = fexp2(sx[i] * KE);
            ey[i] = fexp2(sy[i] * KE);
            float t = ex[i] + ey[i];
            #pragma unroll
            for (int off = 32; off > 0; off >>= 1)
                t += __shfl_xor(t, off, 64);
            if (lane == 0) redw[i * 4 + wv] = t;
        }
        __syncthreads();                   // barrier 3
        float4 av0, av1;
        {
            float S0 = redw[0] + redw[1] + redw[2] + redw[3];
            float S1 = redw[4] + redw[5] + redw[6] + redw[7];
            float S2 = redw[8] + redw[9] + redw[10] + redw[11];
            float S3 = redw[12] + redw[13] + redw[14] + redw[15];
            float r0 = frcp(S0 + 1e-7f), r1 = frcp(S1 + 1e-7f);
            float r2 = frcp(S2 + 1e-7f), r3 = frcp(S3 + 1e-7f);
            av0 = make_float4(ex[0] * r0, ex[1] * r1, ex[2] * r2, ex[3] * r3);
            av1 = make_float4(ey[0] * r0, ey[1] * r1, ey[2] * r2, ey[3] * r3);
        }
        *reinterpret_cast<float4*>(&scT[j0 * 4])     = av0;  // a[*][j0]
        *reinterpret_cast<float4*>(&scT[j0 * 4 + 4]) = av1;  // a[*][j0+1]
    } else {
        __syncthreads();                   // barrier 3 (match)
    }
    __syncthreads();                       // barrier 4: scT ready, pool free

    // Phase D: a @ inps partials, all 512 threads (round-0 shape).
    {
        const int dq = (tid & 31) * 4;
        const int jq = tid >> 5;           // 0..15, 32 j each
        const float* ibase = inps + (size_t)b * SL * DD;
        float4 acc0 = {0,0,0,0}, acc1 = {0,0,0,0}, acc2 = {0,0,0,0}, acc3 = {0,0,0,0};
        const int jb = jq * 32;
        #pragma unroll 4
        for (int jj = 0; jj < 32; ++jj) {
            int jx = jb + jj;
            float4 v  = *reinterpret_cast<const float4*>(ibase + (size_t)jx * DD + dq);
            float4 a4 = *reinterpret_cast<const float4*>(&scT[jx * 4]);  // broadcast
            acc0.x = fmaf(a4.x, v.x, acc0.x); acc0.y = fmaf(a4.x, v.y, acc0.y);
            acc0.z = fmaf(a4.x, v.z, acc0.z); acc0.w = fmaf(a4.x, v.w, acc0.w);
            acc1.x = fmaf(a4.y, v.x, acc1.x); acc1.y = fmaf(a4.y, v.y, acc1.y);
            acc1.z = fmaf(a4.y, v.z, acc1.z); acc1.w = fmaf(a4.y, v.w, acc1.w);
            acc2.x = fmaf(a4.z, v.x, acc2.x); acc2.y = fmaf(a4.z, v.y, acc2.y);
            acc2.z = fmaf(a4.z, v.z, acc2.z); acc2.w = fmaf(a4.z, v.w, acc2.w);
            acc3.x = fmaf(a4.w, v.x, acc3.x); acc3.y = fmaf(a4.w, v.y, acc3.y);
            acc3.z = fmaf(a4.w, v.z, acc3.z); acc3.w = fmaf(a4.w, v.w, acc3.w);
        }
        *reinterpret_cast<float4*>(&pool[(0 * 16 + jq) * DD + dq]) = acc0;
        *reinterpret_cast<float4*>(&pool[(1 * 16 + jq) * DD + dq]) = acc1;
        *reinterpret_cast<float4*>(&pool[(2 * 16 + jq) * DD + dq]) = acc2;
        *reinterpret_cast<float4*>(&pool[(3 * 16 + jq) * DD + dq]) = acc3;
    }
    __syncthreads();                       // barrier 5

    // Phase E: reduce 16 partials per (i, d), write out.
    {
        int i = tid >> 7, d = tid & 127;   // 4 rows x 128 d
        float sum = 0.f;
        #pragma unroll
        for (int q = 0; q < 16; ++q) sum += pool[(i * 16 + q) * DD + d];
        out[(size_t)(bi0 + i) * DD + d] = sum;
    }
}

extern "C" void kernel_launch(void* const* d_in, const int* in_sizes, int n_in,
                              void* d_out, int out_size, void* d_ws, size_t ws_size,
                              hipStream_t stream) {
    const float* inps  = (const float*)d_in[0];  // [B, L, D]
    const float* wei_t = (const float*)d_in[1];  // [D, C]
    const float* wei_x = (const float*)d_in[2];  // [D, C]
    const float* bxh   = (const float*)d_in[3];  // [C]
    const float* wei_a = (const float*)d_in[4];  // [C]
    // d_in[5] = bxa (scalar): uniform shift before softmax -> dropped.
    float* out = (float*)d_out;                  // [B, L, D] fp32

    float* E = (float*)d_ws;                     // [B*L, C]   1 MB
    float* F = E + (size_t)NB * SL * CC;         // [B, C, L]  1 MB

    proj_kernel<<<NB * SL / 2, 256, 0, stream>>>(inps, wei_t, wei_x, bxh, E, F);
    attn_kernel<<<NB * SL / 4, 512, 0, stream>>>(inps, wei_a, E, F, out);
}